// Round 2
// baseline (279.347 us; speedup 1.0000x reference)
//
#include <hip/hip_runtime.h>
#include <math.h>

// Problem constants: B=1, T=384, C=512, H=8, D=64, E=16
#define TT 384
#define CC 512
#define HH 8
#define EE 16

typedef __bf16 bf16_t;
typedef __bf16 bf16x8 __attribute__((ext_vector_type(8)));
typedef float f32x4 __attribute__((ext_vector_type(4)));

__device__ __forceinline__ float wave_reduce_sum(float v) {
#pragma unroll
  for (int off = 32; off >= 1; off >>= 1) v += __shfl_xor(v, off, 64);
  return v;
}
__device__ __forceinline__ float wave_reduce_max(float v) {
#pragma unroll
  for (int off = 32; off >= 1; off >>= 1) v = fmaxf(v, __shfl_xor(v, off, 64));
  return v;
}

// ---------------------------------------------------------------------------
// Canonicalize: detect f32-vs-bf16 on device (ln1_w[0]==1.0 exactly) and
// convert all float tensors into one contiguous bf16 buffer.
// Segment element counts (d_in dict order, skipping int bias_matrix idx 1):
//   x 196608 | ln1_w 512 | ln1_b 512 | w_attn_w 786432 | w_attn_b 1536
//   w_proj_w 262144 | w_proj_b 512 | attn_bias_emb 128 | edge_emb 8192
//   w_edge_k_w 262144 | w_edge_k_b 512 | w_edge_v_w 262144 | w_edge_v_b 512
//   ln2_w 512 | ln2_b 512 | c_fc_w 1048576 | c_fc_b 2048 | c_proj_w 1048576
//   c_proj_b 512            total = 3,882,624 elements
// ---------------------------------------------------------------------------
#define CANON_TOTAL 3882624

struct InPtrs { const void* p[20]; };

__global__ __launch_bounds__(256) void canon_k(InPtrs ip, bf16_t* __restrict__ canon,
                                               int* __restrict__ flag_out) {
  static constexpr int NSEG = 19;
  static constexpr int segidx[NSEG] = {0, 2, 3, 4, 5, 6, 7, 8, 9, 10,
                                       11, 12, 13, 14, 15, 16, 17, 18, 19};
  static constexpr int segend[NSEG] = {
      196608, 197120, 197632, 984064, 985600, 1247744, 1248256, 1248384,
      1256576, 1518720, 1519232, 1781376, 1781888, 1782400, 1782912,
      2831488, 2833536, 3882112, 3882624};

  int isf32 = (((const unsigned int*)ip.p[2])[0] == 0x3F800000u) ? 1 : 0;
  int gid = blockIdx.x * 256 + threadIdx.x;
  if (gid == 0) flag_out[0] = isf32;
  if (gid >= CANON_TOTAL) return;

  int seg = 0, start = 0;
#pragma unroll
  for (int s = 0; s < NSEG; s++) {
    if (gid >= segend[s]) { seg = s + 1; start = segend[s]; }
  }
  int local = gid - start;
  const void* src = ip.p[segidx[seg]];
  float v = isf32 ? ((const float*)src)[local] : (float)((const bf16_t*)src)[local];
  canon[gid] = (bf16_t)v;
}

// canon element offsets
#define OFF_X 0
#define OFF_LN1W 196608
#define OFF_LN1B 197120
#define OFF_WATTN 197632
#define OFF_WATTNB 984064
#define OFF_WPROJ 985600
#define OFF_WPROJB 1247744
#define OFF_ABEMB 1248256
#define OFF_EDGEEMB 1248384
#define OFF_WEKW 1256576
#define OFF_WEKB 1518720
#define OFF_WEVW 1519232
#define OFF_WEVB 1781376
#define OFF_LN2W 1781888
#define OFF_LN2B 1782400
#define OFF_CFCW 1782912
#define OFF_CFCB 2831488
#define OFF_CPROJW 2833536
#define OFF_CPROJB 3882112

// ---------------------------------------------------------------------------
// ek_tab[e][c] = edge_emb[e] . w_edge_k_w[c] + kb[c]   (and same for v table)
// ---------------------------------------------------------------------------
__global__ void edge_tables_k(const bf16_t* __restrict__ edge_emb,
                              const bf16_t* __restrict__ wk, const bf16_t* __restrict__ kb,
                              const bf16_t* __restrict__ wv, const bf16_t* __restrict__ vb,
                              float* __restrict__ ek_tab, float* __restrict__ ev_tab) {
  int gid = blockIdx.x * 256 + threadIdx.x;       // 0..16383
  int table = gid >> 13;
  int e = (gid >> 9) & 15;
  int c = gid & 511;
  const bf16_t* er = edge_emb + e * 512;
  const bf16_t* wr = (table ? wv : wk) + c * 512;
  float a0 = 0.f, a1 = 0.f, a2 = 0.f, a3 = 0.f;
  for (int kk = 0; kk < 512; kk += 4) {
    a0 += (float)er[kk + 0] * (float)wr[kk + 0];
    a1 += (float)er[kk + 1] * (float)wr[kk + 1];
    a2 += (float)er[kk + 2] * (float)wr[kk + 2];
    a3 += (float)er[kk + 3] * (float)wr[kk + 3];
  }
  float acc = (a0 + a1) + (a2 + a3);
  acc += (float)(table ? vb[c] : kb[c]);
  (table ? ev_tab : ek_tab)[e * 512 + c] = acc;
}

// ---------------------------------------------------------------------------
// LayerNorm: one block per row (C=512, 256 threads x 2 elements)
// ---------------------------------------------------------------------------
__global__ void ln_k(const void* __restrict__ xin, int in_f32,
                     const bf16_t* __restrict__ w, const bf16_t* __restrict__ b,
                     bf16_t* __restrict__ out) {
  __shared__ float sh[8];
  int row = blockIdx.x, tid = threadIdx.x;
  float v0, v1;
  if (in_f32) {
    const float* xr = (const float*)xin + (size_t)row * CC;
    v0 = xr[tid]; v1 = xr[tid + 256];
  } else {
    const bf16_t* xr = (const bf16_t*)xin + (size_t)row * CC;
    v0 = (float)xr[tid]; v1 = (float)xr[tid + 256];
  }
  float s = wave_reduce_sum(v0 + v1);
  float q = wave_reduce_sum(v0 * v0 + v1 * v1);
  int wv_ = tid >> 6, ln_ = tid & 63;
  if (ln_ == 0) { sh[wv_] = s; sh[4 + wv_] = q; }
  __syncthreads();
  float stot = sh[0] + sh[1] + sh[2] + sh[3];
  float qtot = sh[4] + sh[5] + sh[6] + sh[7];
  float mu = stot * (1.0f / 512.0f);
  float var = qtot * (1.0f / 512.0f) - mu * mu;
  float rs = rsqrtf(var + 1e-5f);
  out[(size_t)row * CC + tid] =
      (bf16_t)((v0 - mu) * rs * (float)w[tid] + (float)b[tid]);
  out[(size_t)row * CC + tid + 256] =
      (bf16_t)((v1 - mu) * rs * (float)w[tid + 256] + (float)b[tid + 256]);
}

// ---------------------------------------------------------------------------
// NT GEMM: C[m,n] = sum_k A[m,k]*W[n,k] + bias[n]  (A: MxK, W: NxK, row-major)
// MFMA 16x16x32 bf16. Block = 256 thr = 4 waves, each wave 32x32, block 64x64.
// A/B frag: row = lane&15, k = (lane>>4)*8+j ; C/D: col = lane&15,
// row = (lane>>4)*4 + reg.
// MODE 0: ->bf16   MODE 1: gelu ->bf16   MODE 2: +res(bf16) ->f32
// MODE 3: +res(f32) -> d_out (dtype per flag)
// ---------------------------------------------------------------------------
template <int MODE>
__global__ __launch_bounds__(256) void gemm_nt(
    const bf16_t* __restrict__ A, const bf16_t* __restrict__ W,
    const bf16_t* __restrict__ bias, const void* __restrict__ res,
    void* __restrict__ out, int N, int K, const int* __restrict__ flagp) {
  int lane = threadIdx.x & 63;
  int wave = threadIdx.x >> 6;
  int m0 = blockIdx.y * 64 + (wave >> 1) * 32;
  int n0 = blockIdx.x * 64 + (wave & 1) * 32;
  int r16 = lane & 15, quad = lane >> 4;
  int of32 = (MODE == 3) ? flagp[0] : 0;

  f32x4 acc[2][2];
  f32x4 zero = {0.f, 0.f, 0.f, 0.f};
#pragma unroll
  for (int i = 0; i < 2; i++)
#pragma unroll
    for (int j = 0; j < 2; j++) acc[i][j] = zero;

  const bf16_t* Ap = A + (size_t)(m0 + r16) * K + quad * 8;
  const bf16_t* Wp = W + (size_t)(n0 + r16) * K + quad * 8;
  for (int kb = 0; kb < K; kb += 32) {
    bf16x8 af[2], bfr[2];
#pragma unroll
    for (int t = 0; t < 2; t++)
      af[t] = *(const bf16x8*)(Ap + (size_t)t * 16 * K + kb);
#pragma unroll
    for (int t = 0; t < 2; t++)
      bfr[t] = *(const bf16x8*)(Wp + (size_t)t * 16 * K + kb);
#pragma unroll
    for (int i = 0; i < 2; i++)
#pragma unroll
      for (int j = 0; j < 2; j++)
        acc[i][j] = __builtin_amdgcn_mfma_f32_16x16x32_bf16(af[i], bfr[j],
                                                            acc[i][j], 0, 0, 0);
  }

#pragma unroll
  for (int j = 0; j < 2; j++) {
    int col = n0 + j * 16 + r16;
    float bv = (float)bias[col];
#pragma unroll
    for (int i = 0; i < 2; i++) {
#pragma unroll
      for (int r = 0; r < 4; r++) {
        int row = m0 + i * 16 + quad * 4 + r;
        float v = acc[i][j][r] + bv;
        if (MODE == 1) v = 0.5f * v * (1.0f + erff(v * 0.70710678118654752f));
        if (MODE == 2) {
          v += (float)((const bf16_t*)res)[(size_t)row * N + col];
          ((float*)out)[(size_t)row * N + col] = v;
        } else if (MODE == 3) {
          v += ((const float*)res)[(size_t)row * N + col];
          if (of32)
            ((float*)out)[(size_t)row * N + col] = v;
          else
            ((bf16_t*)out)[(size_t)row * N + col] = (bf16_t)v;
        } else {
          ((bf16_t*)out)[(size_t)row * N + col] = (bf16_t)v;
        }
      }
    }
  }
}

// ---------------------------------------------------------------------------
// Attention: one block per (query row i, head h). 256 thr = 4 waves.
// scores[j] = (1/8) sum_d (q[i,hd]*ek[e_ij,hd]) * k[j,hd] + ab[e_ij,h], j<=i
// softmax, then y[i,hd] = sum_j p_j * v[j,hd] * ev[e_ij,hd]
// qkv layout: row t = [q(512) | k(512) | v(512)]
// ---------------------------------------------------------------------------
__global__ __launch_bounds__(256) void attn_k(
    const bf16_t* __restrict__ qkv, const int* __restrict__ bias_matrix,
    const bf16_t* __restrict__ attn_bias_emb, const float* __restrict__ ek_tab,
    const float* __restrict__ ev_tab, bf16_t* __restrict__ ybuf) {
  __shared__ float s[TT];
  __shared__ int ebuf[TT];
  __shared__ float qe[EE * 64];
  __shared__ float evh[EE * 64];
  __shared__ float red[4 * 64];
  __shared__ float absh[EE];
  __shared__ float scr[8];

  int i = blockIdx.x, h = blockIdx.y;
  int tid = threadIdx.x, lane = tid & 63, wave = tid >> 6;
  int n = i + 1;

  for (int j = tid; j < n; j += 256) ebuf[j] = bias_matrix[i * TT + j];
  if (tid < EE) absh[tid] = (float)attn_bias_emb[tid * HH + h];
  for (int idx = tid; idx < EE * 64; idx += 256) {
    int e = idx >> 6, d = idx & 63;
    float qv = (float)qkv[(size_t)i * 1536 + h * 64 + d];
    qe[idx] = qv * ek_tab[e * 512 + h * 64 + d];
    evh[idx] = ev_tab[e * 512 + h * 64 + d];
  }
  __syncthreads();

  // scores: wave per j, lane per d, butterfly reduce over 64 lanes
  for (int j = wave; j < n; j += 4) {
    int e = ebuf[j];
    float kv = (float)qkv[(size_t)j * 1536 + 512 + h * 64 + lane];
    float t = qe[e * 64 + lane] * kv;
    t = wave_reduce_sum(t);
    if (lane == 0) s[j] = t * 0.125f + absh[e];
  }
  __syncthreads();

  // softmax over s[0..n)
  float lm = -1e30f;
  for (int j = tid; j < n; j += 256) lm = fmaxf(lm, s[j]);
  lm = wave_reduce_max(lm);
  if (lane == 0) scr[wave] = lm;
  __syncthreads();
  float mx = fmaxf(fmaxf(scr[0], scr[1]), fmaxf(scr[2], scr[3]));
  float ls = 0.0f;
  for (int j = tid; j < n; j += 256) {
    float p = __expf(s[j] - mx);
    s[j] = p;
    ls += p;
  }
  ls = wave_reduce_sum(ls);
  if (lane == 0) scr[4 + wave] = ls;
  __syncthreads();
  float inv = 1.0f / (scr[4] + scr[5] + scr[6] + scr[7]);

  // y accumulate: wave per j, lane per d, no cross-lane reduce needed
  float acc = 0.0f;
  for (int j = wave; j < n; j += 4) {
    int e = ebuf[j];
    float p = s[j];
    float vv = (float)qkv[(size_t)j * 1536 + 1024 + h * 64 + lane];
    acc += p * vv * evh[e * 64 + lane];
  }
  red[wave * 64 + lane] = acc;
  __syncthreads();
  if (tid < 64) {
    float y = (red[tid] + red[64 + tid] + red[128 + tid] + red[192 + tid]) * inv;
    ybuf[(size_t)i * CC + h * 64 + tid] = (bf16_t)y;
  }
}

// ---------------------------------------------------------------------------
extern "C" void kernel_launch(void* const* d_in, const int* in_sizes, int n_in,
                              void* d_out, int out_size, void* d_ws,
                              size_t ws_size, hipStream_t stream) {
  const int* bias_mat = (const int*)d_in[1];

  char* wp = (char*)d_ws;
  bf16_t* canon = (bf16_t*)wp;  wp += (size_t)CANON_TOTAL * 2;   // 7,765,248 B
  int* flag = (int*)wp;         wp += 16;
  float* ek_tab = (float*)wp;   wp += 16 * 512 * 4;
  float* ev_tab = (float*)wp;   wp += 16 * 512 * 4;
  bf16_t* hbuf = (bf16_t*)wp;   wp += 384 * 512 * 2;
  bf16_t* qkv = (bf16_t*)wp;    wp += 384 * 1536 * 2;
  bf16_t* ybuf = (bf16_t*)wp;   wp += 384 * 512 * 2;
  float* x1 = (float*)wp;       wp += 384 * 512 * 4;
  bf16_t* h2 = (bf16_t*)wp;     wp += 384 * 512 * 2;
  bf16_t* gbuf = (bf16_t*)wp;   wp += 384 * 2048 * 2;

  // 0) detect dtype + canonicalize every float tensor to bf16
  InPtrs ip;
  for (int i = 0; i < 20; i++) ip.p[i] = d_in[i];
  canon_k<<<(CANON_TOTAL + 255) / 256, 256, 0, stream>>>(ip, canon, flag);

  const bf16_t* x = canon + OFF_X;
  // 1) edge projection tables (16 values each)
  edge_tables_k<<<64, 256, 0, stream>>>(canon + OFF_EDGEEMB, canon + OFF_WEKW,
                                        canon + OFF_WEKB, canon + OFF_WEVW,
                                        canon + OFF_WEVB, ek_tab, ev_tab);
  // 2) LN1
  ln_k<<<384, 256, 0, stream>>>(x, 0, canon + OFF_LN1W, canon + OFF_LN1B, hbuf);
  // 3) QKV = h @ w_attn_w.T + b   (384 x 1536, K=512)
  gemm_nt<0><<<dim3(1536 / 64, 384 / 64), 256, 0, stream>>>(
      hbuf, canon + OFF_WATTN, canon + OFF_WATTNB, nullptr, qkv, 1536, 512,
      nullptr);
  // 4) edge-conditioned causal attention
  attn_k<<<dim3(TT, HH), 256, 0, stream>>>(qkv, bias_mat, canon + OFF_ABEMB,
                                           ek_tab, ev_tab, ybuf);
  // 5) x1 = x + y @ w_proj_w.T + b   (fp32 residual stream)
  gemm_nt<2><<<dim3(512 / 64, 384 / 64), 256, 0, stream>>>(
      ybuf, canon + OFF_WPROJ, canon + OFF_WPROJB, x, x1, 512, 512, nullptr);
  // 6) LN2
  ln_k<<<384, 256, 0, stream>>>(x1, 1, canon + OFF_LN2W, canon + OFF_LN2B, h2);
  // 7) fc + exact gelu (384 x 2048, K=512)
  gemm_nt<1><<<dim3(2048 / 64, 384 / 64), 256, 0, stream>>>(
      h2, canon + OFF_CFCW, canon + OFF_CFCB, nullptr, gbuf, 2048, 512,
      nullptr);
  // 8) out = x1 + g @ c_proj_w.T + b  (384 x 512, K=2048) -> d_out
  gemm_nt<3><<<dim3(512 / 64, 384 / 64), 256, 0, stream>>>(
      gbuf, canon + OFF_CPROJW, canon + OFF_CPROJB, x1, d_out, 512, 2048, flag);
}

// Round 3
// 263.357 us; speedup vs baseline: 1.0607x; 1.0607x over previous
//
#include <hip/hip_runtime.h>
#include <math.h>

// Problem constants: B=1, T=384, C=512, H=8, D=64, E=16. Inputs are f32
// (established round 1→2: direct-bf16 reads NaN'd; dtype-detect canon passed).
#define TT 384
#define CC 512
#define HH 8
#define EE 16

typedef __bf16 bf16_t;
typedef __bf16 bf16x8 __attribute__((ext_vector_type(8)));
typedef float f32x4 __attribute__((ext_vector_type(4)));

__device__ __forceinline__ float wave_reduce_sum(float v) {
#pragma unroll
  for (int off = 32; off >= 1; off >>= 1) v += __shfl_xor(v, off, 64);
  return v;
}
__device__ __forceinline__ float wave_reduce_max(float v) {
#pragma unroll
  for (int off = 32; off >= 1; off >>= 1) v = fmaxf(v, __shfl_xor(v, off, 64));
  return v;
}

// ---------------------------------------------------------------------------
// ek_tab[e][c] = edge_emb[e] . w_edge_k_w[c] + kb[c]  (table 1: v analog)
// wave per 16 outputs; lane covers 8 k-elements; 6-shfl reduce per output.
// 16384 outputs / 16 = 1024 waves = 256 blocks x 4 waves.
// ---------------------------------------------------------------------------
__global__ __launch_bounds__(256) void edge_tables_k(
    const float* __restrict__ edge_emb, const float* __restrict__ wk,
    const float* __restrict__ kb, const float* __restrict__ wv,
    const float* __restrict__ vb, float* __restrict__ ek_tab,
    float* __restrict__ ev_tab) {
  int wid = blockIdx.x * 4 + (threadIdx.x >> 6);  // 0..1023
  int lane = threadIdx.x & 63;
  int gbase = wid * 16;
  int table = gbase >> 13;
  int e = (gbase >> 9) & 15;
  int c0 = gbase & 511;
  const float* er = edge_emb + e * 512 + lane * 8;
  f32x4 ea = *(const f32x4*)er;
  f32x4 eb = *(const f32x4*)(er + 4);
  const float* wbase = table ? wv : wk;
  const float* bbase = table ? vb : kb;
  float* obase = (table ? ev_tab : ek_tab) + e * 512;
#pragma unroll
  for (int o = 0; o < 16; o++) {
    int c = c0 + o;
    const float* wr = wbase + (size_t)c * 512 + lane * 8;
    f32x4 wa = *(const f32x4*)wr;
    f32x4 wb = *(const f32x4*)(wr + 4);
    float acc = ea.x * wa.x + ea.y * wa.y + ea.z * wa.z + ea.w * wa.w +
                eb.x * wb.x + eb.y * wb.y + eb.z * wb.z + eb.w * wb.w;
    acc = wave_reduce_sum(acc);
    if (lane == 0) obase[c] = acc + bbase[c];
  }
}

// ---------------------------------------------------------------------------
// LayerNorm: one block per row (C=512, 256 threads x 2 elements). f32 in,
// f32 w/b, bf16 out.
// ---------------------------------------------------------------------------
__global__ void ln_k(const float* __restrict__ xin, const float* __restrict__ w,
                     const float* __restrict__ b, bf16_t* __restrict__ out) {
  __shared__ float sh[8];
  int row = blockIdx.x, tid = threadIdx.x;
  const float* xr = xin + (size_t)row * CC;
  float v0 = xr[tid], v1 = xr[tid + 256];
  float s = wave_reduce_sum(v0 + v1);
  float q = wave_reduce_sum(v0 * v0 + v1 * v1);
  int wv_ = tid >> 6, ln_ = tid & 63;
  if (ln_ == 0) { sh[wv_] = s; sh[4 + wv_] = q; }
  __syncthreads();
  float stot = sh[0] + sh[1] + sh[2] + sh[3];
  float qtot = sh[4] + sh[5] + sh[6] + sh[7];
  float mu = stot * (1.0f / 512.0f);
  float var = qtot * (1.0f / 512.0f) - mu * mu;
  float rs = rsqrtf(var + 1e-5f);
  out[(size_t)row * CC + tid] = (bf16_t)((v0 - mu) * rs * w[tid] + b[tid]);
  out[(size_t)row * CC + tid + 256] =
      (bf16_t)((v1 - mu) * rs * w[tid + 256] + b[tid + 256]);
}

// ---------------------------------------------------------------------------
// NT GEMM: C[m,n] = sum_k A[m,k]*W[n,k] + bias[n]
// A: bf16 MxK row-major (our intermediate). W: f32 NxK row-major (input
// weights, converted to bf16 in the fragment load). MFMA 16x16x32 bf16.
// Block 256 thr = 4 waves, wave 32x32, block 64x64.
// A/B frag: row=lane&15, k=(lane>>4)*8+j ; C/D: col=lane&15, row=(lane>>4)*4+r
// MODE 0: ->bf16  MODE 1: gelu->bf16  MODE 2: +res(f32)->f32
// MODE 3: +res(f32)->f32
// ---------------------------------------------------------------------------
__device__ __forceinline__ bf16x8 load_w_frag(const float* p) {
  f32x4 a = *(const f32x4*)p;
  f32x4 b = *(const f32x4*)(p + 4);
  bf16x8 r;
  r[0] = (bf16_t)a.x; r[1] = (bf16_t)a.y; r[2] = (bf16_t)a.z; r[3] = (bf16_t)a.w;
  r[4] = (bf16_t)b.x; r[5] = (bf16_t)b.y; r[6] = (bf16_t)b.z; r[7] = (bf16_t)b.w;
  return r;
}

template <int MODE>
__global__ __launch_bounds__(256) void gemm_nt(
    const bf16_t* __restrict__ A, const float* __restrict__ W,
    const float* __restrict__ bias, const float* __restrict__ res,
    void* __restrict__ out, int N, int K) {
  int lane = threadIdx.x & 63;
  int wave = threadIdx.x >> 6;
  int m0 = blockIdx.y * 64 + (wave >> 1) * 32;
  int n0 = blockIdx.x * 64 + (wave & 1) * 32;
  int r16 = lane & 15, quad = lane >> 4;

  f32x4 acc[2][2];
  f32x4 zero = {0.f, 0.f, 0.f, 0.f};
#pragma unroll
  for (int i = 0; i < 2; i++)
#pragma unroll
    for (int j = 0; j < 2; j++) acc[i][j] = zero;

  const bf16_t* Ap = A + (size_t)(m0 + r16) * K + quad * 8;
  const float* Wp = W + (size_t)(n0 + r16) * K + quad * 8;
  for (int kb = 0; kb < K; kb += 32) {
    bf16x8 af[2], bfr[2];
#pragma unroll
    for (int t = 0; t < 2; t++)
      af[t] = *(const bf16x8*)(Ap + (size_t)t * 16 * K + kb);
#pragma unroll
    for (int t = 0; t < 2; t++)
      bfr[t] = load_w_frag(Wp + (size_t)t * 16 * K + kb);
#pragma unroll
    for (int i = 0; i < 2; i++)
#pragma unroll
      for (int j = 0; j < 2; j++)
        acc[i][j] = __builtin_amdgcn_mfma_f32_16x16x32_bf16(af[i], bfr[j],
                                                            acc[i][j], 0, 0, 0);
  }

#pragma unroll
  for (int j = 0; j < 2; j++) {
    int col = n0 + j * 16 + r16;
    float bv = bias[col];
#pragma unroll
    for (int i = 0; i < 2; i++) {
#pragma unroll
      for (int r = 0; r < 4; r++) {
        int row = m0 + i * 16 + quad * 4 + r;
        float v = acc[i][j][r] + bv;
        if (MODE == 1) v = 0.5f * v * (1.0f + erff(v * 0.70710678118654752f));
        if (MODE == 2 || MODE == 3) {
          v += res[(size_t)row * N + col];
          ((float*)out)[(size_t)row * N + col] = v;
        } else {
          ((bf16_t*)out)[(size_t)row * N + col] = (bf16_t)v;
        }
      }
    }
  }
}

// ---------------------------------------------------------------------------
// Attention: one block per (query row i, head h). 256 thr = 4 waves.
// scores[j] = (1/8) sum_d (q[i,hd]*ek[e_ij,hd]) * k[j,hd] + ab[e_ij,h], j<=i
// softmax, then y[i,hd] = sum_j p_j * v[j,hd] * ev[e_ij,hd]
// Score phase: lane-per-j, K staged in LDS (16B chunks, XOR-swizzled so the
// 8 chunk-slots of 8 consecutive rows spread across all 32 banks).
// PV phase: lane-per-d, wave-per-j (no cross-lane reduce).
// ---------------------------------------------------------------------------
#define TJ 256
__global__ __launch_bounds__(256) void attn_k(
    const bf16_t* __restrict__ qkv, const int* __restrict__ bias_matrix,
    const float* __restrict__ attn_bias_emb, const float* __restrict__ ek_tab,
    const float* __restrict__ ev_tab, bf16_t* __restrict__ ybuf) {
  __shared__ float s[TT];
  __shared__ int ebuf[TT];
  __shared__ float qe[EE][68];   // padded: 68 f32 = 272 B rows (16B aligned)
  __shared__ float evh[EE * 64];
  __shared__ float red[4 * 64];
  __shared__ float absh[EE];
  __shared__ float scr[8];
  __shared__ uint4 ktile[TJ * 8];  // 256 rows x 8 x 16B = 32 KB, swizzled

  int i = blockIdx.x, h = blockIdx.y;
  int tid = threadIdx.x, lane = tid & 63, wave = tid >> 6;
  int n = i + 1;

  for (int j = tid; j < n; j += 256) ebuf[j] = bias_matrix[i * TT + j];
  if (tid < EE) absh[tid] = attn_bias_emb[tid * HH + h];
  for (int idx = tid; idx < EE * 64; idx += 256) {
    int e = idx >> 6, d = idx & 63;
    float qv = (float)qkv[(size_t)i * 1536 + h * 64 + d];
    qe[e][d] = qv * ek_tab[e * 512 + h * 64 + d];
    evh[idx] = ev_tab[e * 512 + h * 64 + d];
  }
  __syncthreads();

  // ---- score phase over j-tiles of TJ
  for (int jb = 0; jb < n; jb += TJ) {
    int cnt = min(TJ, n - jb);
    // stage K rows [jb, jb+cnt): thread t stages chunk (t&7) of rows
    // p*32+(t>>3); swizzled slot = chunk ^ (row&7)
#pragma unroll
    for (int p = 0; p < 8; p++) {
      int row = p * 32 + (tid >> 3);
      int ch = tid & 7;
      if (row < cnt) {
        const uint4* src = (const uint4*)(qkv + (size_t)(jb + row) * 1536 +
                                          512 + h * 64 + ch * 8);
        ktile[row * 8 + (ch ^ (row & 7))] = *src;
      }
    }
    __syncthreads();
    int jl = tid;
    if (jl < cnt) {
      int j = jb + jl;
      int e = ebuf[j];
      float acc = 0.f;
#pragma unroll
      for (int dg = 0; dg < 8; dg++) {
        uint4 kk = ktile[jl * 8 + (dg ^ (jl & 7))];
        bf16x8 kv = *reinterpret_cast<const bf16x8*>(&kk);
        f32x4 qa = *(const f32x4*)&qe[e][dg * 8];
        f32x4 qb = *(const f32x4*)&qe[e][dg * 8 + 4];
        acc += (float)kv[0] * qa.x + (float)kv[1] * qa.y +
               (float)kv[2] * qa.z + (float)kv[3] * qa.w +
               (float)kv[4] * qb.x + (float)kv[5] * qb.y +
               (float)kv[6] * qb.z + (float)kv[7] * qb.w;
      }
      s[j] = acc * 0.125f + absh[e];
    }
    __syncthreads();  // before next tile overwrites ktile
  }

  // ---- softmax over s[0..n)
  float lm = -1e30f;
  for (int j = tid; j < n; j += 256) lm = fmaxf(lm, s[j]);
  lm = wave_reduce_max(lm);
  if (lane == 0) scr[wave] = lm;
  __syncthreads();
  float mx = fmaxf(fmaxf(scr[0], scr[1]), fmaxf(scr[2], scr[3]));
  float ls = 0.0f;
  for (int j = tid; j < n; j += 256) {
    float p = __expf(s[j] - mx);
    s[j] = p;
    ls += p;
  }
  ls = wave_reduce_sum(ls);
  if (lane == 0) scr[4 + wave] = ls;
  __syncthreads();
  float inv = 1.0f / (scr[4] + scr[5] + scr[6] + scr[7]);

  // ---- PV: wave per j, lane per d
  float acc = 0.0f;
  for (int j = wave; j < n; j += 4) {
    int e = ebuf[j];
    float p = s[j];
    float vv = (float)qkv[(size_t)j * 1536 + 1024 + h * 64 + lane];
    acc += p * vv * evh[e * 64 + lane];
  }
  red[wave * 64 + lane] = acc;
  __syncthreads();
  if (tid < 64) {
    float y = (red[tid] + red[64 + tid] + red[128 + tid] + red[192 + tid]) * inv;
    ybuf[(size_t)i * CC + h * 64 + tid] = (bf16_t)y;
  }
}

// ---------------------------------------------------------------------------
extern "C" void kernel_launch(void* const* d_in, const int* in_sizes, int n_in,
                              void* d_out, int out_size, void* d_ws,
                              size_t ws_size, hipStream_t stream) {
  const float* x = (const float*)d_in[0];
  const int* bias_mat = (const int*)d_in[1];
  const float* ln1_w = (const float*)d_in[2];
  const float* ln1_b = (const float*)d_in[3];
  const float* w_attn_w = (const float*)d_in[4];
  const float* w_attn_b = (const float*)d_in[5];
  const float* w_proj_w = (const float*)d_in[6];
  const float* w_proj_b = (const float*)d_in[7];
  const float* attn_bias_emb = (const float*)d_in[8];
  const float* edge_emb = (const float*)d_in[9];
  const float* w_edge_k_w = (const float*)d_in[10];
  const float* w_edge_k_b = (const float*)d_in[11];
  const float* w_edge_v_w = (const float*)d_in[12];
  const float* w_edge_v_b = (const float*)d_in[13];
  const float* ln2_w = (const float*)d_in[14];
  const float* ln2_b = (const float*)d_in[15];
  const float* c_fc_w = (const float*)d_in[16];
  const float* c_fc_b = (const float*)d_in[17];
  const float* c_proj_w = (const float*)d_in[18];
  const float* c_proj_b = (const float*)d_in[19];

  char* wp = (char*)d_ws;
  float* ek_tab = (float*)wp;   wp += 16 * 512 * 4;
  float* ev_tab = (float*)wp;   wp += 16 * 512 * 4;
  bf16_t* hbuf = (bf16_t*)wp;   wp += 384 * 512 * 2;
  bf16_t* qkv = (bf16_t*)wp;    wp += 384 * 1536 * 2;
  bf16_t* ybuf = (bf16_t*)wp;   wp += 384 * 512 * 2;
  float* x1 = (float*)wp;       wp += 384 * 512 * 4;
  bf16_t* h2 = (bf16_t*)wp;     wp += 384 * 512 * 2;
  bf16_t* gbuf = (bf16_t*)wp;   wp += 384 * 2048 * 2;

  // 1) edge projection tables (16 values each)
  edge_tables_k<<<256, 256, 0, stream>>>(edge_emb, w_edge_k_w, w_edge_k_b,
                                         w_edge_v_w, w_edge_v_b, ek_tab, ev_tab);
  // 2) LN1
  ln_k<<<384, 256, 0, stream>>>(x, ln1_w, ln1_b, hbuf);
  // 3) QKV = h @ w_attn_w.T + b   (384 x 1536, K=512)
  gemm_nt<0><<<dim3(1536 / 64, 384 / 64), 256, 0, stream>>>(
      hbuf, w_attn_w, w_attn_b, nullptr, qkv, 1536, 512);
  // 4) edge-conditioned causal attention
  attn_k<<<dim3(TT, HH), 256, 0, stream>>>(qkv, bias_mat, attn_bias_emb,
                                           ek_tab, ev_tab, ybuf);
  // 5) x1 = x + y @ w_proj_w.T + b   (fp32 residual stream)
  gemm_nt<2><<<dim3(512 / 64, 384 / 64), 256, 0, stream>>>(
      ybuf, w_proj_w, w_proj_b, x, x1, 512, 512);
  // 6) LN2
  ln_k<<<384, 256, 0, stream>>>(x1, ln2_w, ln2_b, h2);
  // 7) fc + exact gelu (384 x 2048, K=512)
  gemm_nt<1><<<dim3(2048 / 64, 384 / 64), 256, 0, stream>>>(
      h2, c_fc_w, c_fc_b, nullptr, gbuf, 2048, 512);
  // 8) out = x1 + g @ c_proj_w.T + b  (384 x 512, K=2048) -> f32 d_out
  gemm_nt<3><<<dim3(512 / 64, 384 / 64), 256, 0, stream>>>(
      gbuf, c_proj_w, c_proj_b, x1, (float*)d_out, 512, 2048);
}

// Round 4
// 182.592 us; speedup vs baseline: 1.5299x; 1.4423x over previous
//
#include <hip/hip_runtime.h>
#include <math.h>

// Problem constants: B=1, T=384, C=512, H=8, D=64, E=16. Inputs are f32.
#define TT 384
#define CC 512
#define HH 8
#define EE 16

typedef __bf16 bf16_t;
typedef __bf16 bf16x8 __attribute__((ext_vector_type(8)));
typedef __bf16 bf16x4v __attribute__((ext_vector_type(4)));
typedef float f32x4 __attribute__((ext_vector_type(4)));

__device__ __forceinline__ float wave_reduce_sum(float v) {
#pragma unroll
  for (int off = 32; off >= 1; off >>= 1) v += __shfl_xor(v, off, 64);
  return v;
}
__device__ __forceinline__ float wave_reduce_max(float v) {
#pragma unroll
  for (int off = 32; off >= 1; off >>= 1) v = fmaxf(v, __shfl_xor(v, off, 64));
  return v;
}

// ---------------------------------------------------------------------------
// Fused pre-pass: blocks [0,384) do LayerNorm1 rows; blocks [384,640) build
// the edge projection tables ek_tab/ev_tab (16 e-values each).
// ---------------------------------------------------------------------------
__global__ __launch_bounds__(256) void pre_k(
    const float* __restrict__ x, const float* __restrict__ ln1_w,
    const float* __restrict__ ln1_b, bf16_t* __restrict__ hbuf,
    const float* __restrict__ edge_emb, const float* __restrict__ wk,
    const float* __restrict__ kb, const float* __restrict__ wv,
    const float* __restrict__ vb, float* __restrict__ ek_tab,
    float* __restrict__ ev_tab) {
  __shared__ float sh[8];
  int tid = threadIdx.x;
  if (blockIdx.x < 384) {
    // ---- LayerNorm
    int row = blockIdx.x;
    const float* xr = x + (size_t)row * CC;
    float v0 = xr[tid], v1 = xr[tid + 256];
    float s = wave_reduce_sum(v0 + v1);
    float q = wave_reduce_sum(v0 * v0 + v1 * v1);
    int wv_ = tid >> 6, ln_ = tid & 63;
    if (ln_ == 0) { sh[wv_] = s; sh[4 + wv_] = q; }
    __syncthreads();
    float stot = sh[0] + sh[1] + sh[2] + sh[3];
    float qtot = sh[4] + sh[5] + sh[6] + sh[7];
    float mu = stot * (1.0f / 512.0f);
    float var = qtot * (1.0f / 512.0f) - mu * mu;
    float rs = rsqrtf(var + 1e-5f);
    hbuf[(size_t)row * CC + tid] =
        (bf16_t)((v0 - mu) * rs * ln1_w[tid] + ln1_b[tid]);
    hbuf[(size_t)row * CC + tid + 256] =
        (bf16_t)((v1 - mu) * rs * ln1_w[tid + 256] + ln1_b[tid + 256]);
  } else {
    // ---- edge tables: wave per 16 outputs
    int wid = (blockIdx.x - 384) * 4 + (tid >> 6);  // 0..1023
    int lane = tid & 63;
    int gbase = wid * 16;
    int table = gbase >> 13;
    int e = (gbase >> 9) & 15;
    int c0 = gbase & 511;
    const float* er = edge_emb + e * 512 + lane * 8;
    f32x4 ea = *(const f32x4*)er;
    f32x4 eb = *(const f32x4*)(er + 4);
    const float* wbase = table ? wv : wk;
    const float* bbase = table ? vb : kb;
    float* obase = (table ? ev_tab : ek_tab) + e * 512;
#pragma unroll
    for (int o = 0; o < 16; o++) {
      int c = c0 + o;
      const float* wr = wbase + (size_t)c * 512 + lane * 8;
      f32x4 wa = *(const f32x4*)wr;
      f32x4 wb = *(const f32x4*)(wr + 4);
      float acc = ea.x * wa.x + ea.y * wa.y + ea.z * wa.z + ea.w * wa.w +
                  eb.x * wb.x + eb.y * wb.y + eb.z * wb.z + eb.w * wb.w;
      acc = wave_reduce_sum(acc);
      if (lane == 0) obase[c] = acc + bbase[c];
    }
  }
}

// ---------------------------------------------------------------------------
// LayerNorm2: one block per row (f32 in, bf16 out)
// ---------------------------------------------------------------------------
__global__ void ln_k(const float* __restrict__ xin, const float* __restrict__ w,
                     const float* __restrict__ b, bf16_t* __restrict__ out) {
  __shared__ float sh[8];
  int row = blockIdx.x, tid = threadIdx.x;
  const float* xr = xin + (size_t)row * CC;
  float v0 = xr[tid], v1 = xr[tid + 256];
  float s = wave_reduce_sum(v0 + v1);
  float q = wave_reduce_sum(v0 * v0 + v1 * v1);
  int wv_ = tid >> 6, ln_ = tid & 63;
  if (ln_ == 0) { sh[wv_] = s; sh[4 + wv_] = q; }
  __syncthreads();
  float stot = sh[0] + sh[1] + sh[2] + sh[3];
  float qtot = sh[4] + sh[5] + sh[6] + sh[7];
  float mu = stot * (1.0f / 512.0f);
  float var = qtot * (1.0f / 512.0f) - mu * mu;
  float rs = rsqrtf(var + 1e-5f);
  out[(size_t)row * CC + tid] = (bf16_t)((v0 - mu) * rs * w[tid] + b[tid]);
  out[(size_t)row * CC + tid + 256] =
      (bf16_t)((v1 - mu) * rs * w[tid + 256] + b[tid + 256]);
}

// ---------------------------------------------------------------------------
// Split-K NT GEMM: C[m,n] = sum_k A[m,k]*W[n,k] + bias[n]
// Block 256 thr = 4 waves; block tile 32x32; wave w covers K-chunk w*K/4.
// Partials reduced through LDS. A bf16, W f32 (converted in the frag load).
// A/B frag: row=lane&15, k=(lane>>4)*8+j ; C/D: col=lane&15, row=(lane>>4)*4+r
// MODE 0: ->bf16  MODE 1: gelu->bf16  MODE 2: +res(f32)->f32
// MODE 3: +res(f32)->f32
// ---------------------------------------------------------------------------
__device__ __forceinline__ bf16x8 load_w_frag(const float* p) {
  f32x4 a = *(const f32x4*)p;
  f32x4 b = *(const f32x4*)(p + 4);
  bf16x8 r;
  r[0] = (bf16_t)a.x; r[1] = (bf16_t)a.y; r[2] = (bf16_t)a.z; r[3] = (bf16_t)a.w;
  r[4] = (bf16_t)b.x; r[5] = (bf16_t)b.y; r[6] = (bf16_t)b.z; r[7] = (bf16_t)b.w;
  return r;
}

template <int MODE>
__global__ __launch_bounds__(256) void gemm_sk(
    const bf16_t* __restrict__ A, const float* __restrict__ W,
    const float* __restrict__ bias, const float* __restrict__ res,
    void* __restrict__ out, int N, int K) {
  __shared__ float part[4][32][32];  // 16 KB
  int tid = threadIdx.x;
  int lane = tid & 63, wave = tid >> 6;
  int m0 = blockIdx.y * 32, n0 = blockIdx.x * 32;
  int r16 = lane & 15, quad = lane >> 4;
  int kchunk = K >> 2;
  int k0 = wave * kchunk;

  f32x4 acc[2][2];
  f32x4 zero = {0.f, 0.f, 0.f, 0.f};
#pragma unroll
  for (int i = 0; i < 2; i++)
#pragma unroll
    for (int j = 0; j < 2; j++) acc[i][j] = zero;

  const bf16_t* Ap = A + (size_t)(m0 + r16) * K + k0 + quad * 8;
  const float* Wp = W + (size_t)(n0 + r16) * K + k0 + quad * 8;
  for (int kb = 0; kb < kchunk; kb += 32) {
    bf16x8 af[2], bfr[2];
#pragma unroll
    for (int t = 0; t < 2; t++)
      af[t] = *(const bf16x8*)(Ap + (size_t)t * 16 * K + kb);
#pragma unroll
    for (int t = 0; t < 2; t++)
      bfr[t] = load_w_frag(Wp + (size_t)t * 16 * K + kb);
#pragma unroll
    for (int i = 0; i < 2; i++)
#pragma unroll
      for (int j = 0; j < 2; j++)
        acc[i][j] = __builtin_amdgcn_mfma_f32_16x16x32_bf16(af[i], bfr[j],
                                                            acc[i][j], 0, 0, 0);
  }

#pragma unroll
  for (int i = 0; i < 2; i++)
#pragma unroll
    for (int j = 0; j < 2; j++)
#pragma unroll
      for (int r = 0; r < 4; r++)
        part[wave][i * 16 + quad * 4 + r][j * 16 + r16] = acc[i][j][r];
  __syncthreads();

  int row = tid >> 3, c4 = (tid & 7) * 4;
  f32x4 v = *(const f32x4*)&part[0][row][c4];
  v += *(const f32x4*)&part[1][row][c4];
  v += *(const f32x4*)&part[2][row][c4];
  v += *(const f32x4*)&part[3][row][c4];
  int grow = m0 + row, gcol = n0 + c4;
  v += *(const f32x4*)(bias + gcol);
  if (MODE == 1) {
#pragma unroll
    for (int t = 0; t < 4; t++)
      v[t] = 0.5f * v[t] * (1.0f + erff(v[t] * 0.70710678118654752f));
  }
  if (MODE == 2 || MODE == 3) {
    v += *(const f32x4*)(res + (size_t)grow * N + gcol);
    *(f32x4*)((float*)out + (size_t)grow * N + gcol) = v;
  } else {
    bf16x4v o;
#pragma unroll
    for (int t = 0; t < 4; t++) o[t] = (bf16_t)v[t];
    *(bf16x4v*)((bf16_t*)out + (size_t)grow * N + gcol) = o;
  }
}

// ---------------------------------------------------------------------------
// Attention: one block per (query row i, head h). 256 thr = 4 waves.
// scores[j] = (1/8) sum_d (q[i,hd]*ek[e_ij,hd]) * k[j,hd] + ab[e_ij,h], j<=i
// Score phase: lane-per-j, K rows read directly from global (L2-resident,
// 8 independent 16B loads per lane). PV: wave-per-j, lane-per-d.
// LDS ~13 KB -> 7-8 blocks/CU.
// ---------------------------------------------------------------------------
__global__ __launch_bounds__(256) void attn_k(
    const bf16_t* __restrict__ qkv, const int* __restrict__ bias_matrix,
    const float* __restrict__ attn_bias_emb, const float* __restrict__ ek_tab,
    const float* __restrict__ ev_tab, bf16_t* __restrict__ ybuf) {
  __shared__ float s[TT];
  __shared__ int ebuf[TT];
  __shared__ float qe[EE][68];   // 272 B rows, 16B aligned
  __shared__ float evh[EE * 64];
  __shared__ float red[4 * 64];
  __shared__ float absh[EE];
  __shared__ float scr[8];

  int i = blockIdx.x, h = blockIdx.y;
  int tid = threadIdx.x, lane = tid & 63, wave = tid >> 6;
  int n = i + 1;

  for (int j = tid; j < n; j += 256) ebuf[j] = bias_matrix[i * TT + j];
  if (tid < EE) absh[tid] = attn_bias_emb[tid * HH + h];
  for (int idx = tid; idx < EE * 64; idx += 256) {
    int e = idx >> 6, d = idx & 63;
    float qv = (float)qkv[(size_t)i * 1536 + h * 64 + d];
    qe[e][d] = qv * ek_tab[e * 512 + h * 64 + d];
    evh[idx] = ev_tab[e * 512 + h * 64 + d];
  }
  __syncthreads();

  // ---- scores: lane per j, direct global K reads
  for (int jl = tid; jl < n; jl += 256) {
    int e = ebuf[jl];
    const uint4* kp = (const uint4*)(qkv + (size_t)jl * 1536 + 512 + h * 64);
    uint4 kr[8];
#pragma unroll
    for (int dg = 0; dg < 8; dg++) kr[dg] = kp[dg];
    float acc = 0.f;
#pragma unroll
    for (int dg = 0; dg < 8; dg++) {
      bf16x8 kv = *reinterpret_cast<const bf16x8*>(&kr[dg]);
      f32x4 qa = *(const f32x4*)&qe[e][dg * 8];
      f32x4 qb = *(const f32x4*)&qe[e][dg * 8 + 4];
      acc += (float)kv[0] * qa.x + (float)kv[1] * qa.y +
             (float)kv[2] * qa.z + (float)kv[3] * qa.w +
             (float)kv[4] * qb.x + (float)kv[5] * qb.y +
             (float)kv[6] * qb.z + (float)kv[7] * qb.w;
    }
    s[jl] = acc * 0.125f + absh[e];
  }
  __syncthreads();

  // ---- softmax over s[0..n)
  float lm = -1e30f;
  for (int j = tid; j < n; j += 256) lm = fmaxf(lm, s[j]);
  lm = wave_reduce_max(lm);
  if (lane == 0) scr[wave] = lm;
  __syncthreads();
  float mx = fmaxf(fmaxf(scr[0], scr[1]), fmaxf(scr[2], scr[3]));
  float ls = 0.0f;
  for (int j = tid; j < n; j += 256) {
    float p = __expf(s[j] - mx);
    s[j] = p;
    ls += p;
  }
  ls = wave_reduce_sum(ls);
  if (lane == 0) scr[4 + wave] = ls;
  __syncthreads();
  float inv = 1.0f / (scr[4] + scr[5] + scr[6] + scr[7]);

  // ---- PV: wave per j, lane per d (unrolled x2 for load ILP)
  float acc = 0.0f;
  int j = wave;
  for (; j + 4 < n; j += 8) {
    int e0 = ebuf[j], e1 = ebuf[j + 4];
    float p0 = s[j], p1 = s[j + 4];
    float v0 = (float)qkv[(size_t)j * 1536 + 1024 + h * 64 + lane];
    float v1 = (float)qkv[(size_t)(j + 4) * 1536 + 1024 + h * 64 + lane];
    acc += p0 * v0 * evh[e0 * 64 + lane] + p1 * v1 * evh[e1 * 64 + lane];
  }
  for (; j < n; j += 4) {
    int e = ebuf[j];
    float vv = (float)qkv[(size_t)j * 1536 + 1024 + h * 64 + lane];
    acc += s[j] * vv * evh[e * 64 + lane];
  }
  red[wave * 64 + lane] = acc;
  __syncthreads();
  if (tid < 64) {
    float y = (red[tid] + red[64 + tid] + red[128 + tid] + red[192 + tid]) * inv;
    ybuf[(size_t)i * CC + h * 64 + tid] = (bf16_t)y;
  }
}

// ---------------------------------------------------------------------------
extern "C" void kernel_launch(void* const* d_in, const int* in_sizes, int n_in,
                              void* d_out, int out_size, void* d_ws,
                              size_t ws_size, hipStream_t stream) {
  const float* x = (const float*)d_in[0];
  const int* bias_mat = (const int*)d_in[1];
  const float* ln1_w = (const float*)d_in[2];
  const float* ln1_b = (const float*)d_in[3];
  const float* w_attn_w = (const float*)d_in[4];
  const float* w_attn_b = (const float*)d_in[5];
  const float* w_proj_w = (const float*)d_in[6];
  const float* w_proj_b = (const float*)d_in[7];
  const float* attn_bias_emb = (const float*)d_in[8];
  const float* edge_emb = (const float*)d_in[9];
  const float* w_edge_k_w = (const float*)d_in[10];
  const float* w_edge_k_b = (const float*)d_in[11];
  const float* w_edge_v_w = (const float*)d_in[12];
  const float* w_edge_v_b = (const float*)d_in[13];
  const float* ln2_w = (const float*)d_in[14];
  const float* ln2_b = (const float*)d_in[15];
  const float* c_fc_w = (const float*)d_in[16];
  const float* c_fc_b = (const float*)d_in[17];
  const float* c_proj_w = (const float*)d_in[18];
  const float* c_proj_b = (const float*)d_in[19];

  char* wp = (char*)d_ws;
  float* ek_tab = (float*)wp;   wp += 16 * 512 * 4;
  float* ev_tab = (float*)wp;   wp += 16 * 512 * 4;
  bf16_t* hbuf = (bf16_t*)wp;   wp += 384 * 512 * 2;
  bf16_t* qkv = (bf16_t*)wp;    wp += 384 * 1536 * 2;
  bf16_t* ybuf = (bf16_t*)wp;   wp += 384 * 512 * 2;
  float* x1 = (float*)wp;       wp += 384 * 512 * 4;
  bf16_t* h2 = (bf16_t*)wp;     wp += 384 * 512 * 2;
  bf16_t* gbuf = (bf16_t*)wp;   wp += 384 * 2048 * 2;

  // 1) LN1 + edge tables (fused, independent work)
  pre_k<<<640, 256, 0, stream>>>(x, ln1_w, ln1_b, hbuf, edge_emb, w_edge_k_w,
                                 w_edge_k_b, w_edge_v_w, w_edge_v_b, ek_tab,
                                 ev_tab);
  // 2) QKV = h @ w_attn_w.T + b   (384 x 1536, K=512)  576 blocks
  gemm_sk<0><<<dim3(48, 12), 256, 0, stream>>>(hbuf, w_attn_w, w_attn_b,
                                               nullptr, qkv, 1536, 512);
  // 3) edge-conditioned causal attention
  attn_k<<<dim3(TT, HH), 256, 0, stream>>>(qkv, bias_mat, attn_bias_emb,
                                           ek_tab, ev_tab, ybuf);
  // 4) x1 = x + y @ w_proj_w.T + b   (384 x 512, K=512)  192 blocks
  gemm_sk<2><<<dim3(16, 12), 256, 0, stream>>>(ybuf, w_proj_w, w_proj_b, x, x1,
                                               512, 512);
  // 5) LN2
  ln_k<<<384, 256, 0, stream>>>(x1, ln2_w, ln2_b, h2);
  // 6) fc + exact gelu (384 x 2048, K=512)  768 blocks
  gemm_sk<1><<<dim3(64, 12), 256, 0, stream>>>(h2, c_fc_w, c_fc_b, nullptr,
                                               gbuf, 2048, 512);
  // 7) out = x1 + g @ c_proj_w.T + b  (384 x 512, K=2048)  192 blocks
  gemm_sk<3><<<dim3(16, 12), 256, 0, stream>>>(gbuf, c_proj_w, c_proj_b, x1,
                                               (float*)d_out, 512, 2048);
}